// Round 17
// baseline (296.846 us; speedup 1.0000x reference)
//
#include <hip/hip_runtime.h>
#include <hip/hip_fp16.h>

#define N_NODES 50000
#define N0_ 20000
#define N1_ 15000
#define N2_ 15000
#define E_EDGES 800000
#define H_ 128
#define C_ 64

#define PB0 ((N0_ + 63) / 64)              // 313
#define PB1 ((N1_ + 63) / 64)              // 235
#define PB2 ((N2_ + 63) / 64)              // 235
#define PB_TOTAL (PB0 + PB1 + PB2)         // 783
#define EB ((E_EDGES + 255) / 256)         // 3125
#define SB ((N_NODES + 255) / 256)         // 196
#define FB ((N_NODES + 63) / 64)           // 782

// ---- A-tile loaders: fp32 direct, fp16 -> fp32 convert (FMA stays fp32) ----
__device__ __forceinline__ float4 load_a4(const float* A, size_t idx) {
    return *reinterpret_cast<const float4*>(&A[idx]);
}
__device__ __forceinline__ float4 load_a4(const __half* A, size_t idx) {
    __half2 p0 = *reinterpret_cast<const __half2*>(&A[idx]);
    __half2 p1 = *reinterpret_cast<const __half2*>(&A[idx + 2]);
    float2 f0 = __half22float2(p0), f1 = __half22float2(p1);
    return make_float4(f0.x, f0.y, f1.x, f1.y);
}

// ---------------- GEMM block (64-row tile, R3/R8/R10-proven) ----------------
// A transposed in LDS (stride 68); B-reads scalar stride-1 across tx (conflict-free).
// R11-R15 ledger: DEPTH-4, MFMA x2, dot2 x2 all regressed; this is the proven best.

template <int TN, bool BIAS, bool RELU, bool SCALE, typename IT, typename OT>
__device__ __forceinline__ void gemm_block(
    const IT* __restrict__ A, const float* __restrict__ W,
    const float* __restrict__ bias, const float* __restrict__ rowscale,
    OT* __restrict__ out, int M, int K, int m0, float* As, float* Bs) {
    constexpr int NJ = TN / 32;
    constexpr int TN4 = TN / 4;
    int tid = threadIdx.x;
    int tx = tid & 31;
    int ty = tid >> 5;

    float acc[8][NJ];
#pragma unroll
    for (int i = 0; i < 8; i++)
#pragma unroll
        for (int j = 0; j < NJ; j++) acc[i][j] = 0.f;

    for (int k0 = 0; k0 < K; k0 += 32) {
#pragma unroll
        for (int t0 = 0; t0 < 2; t0++) {
            int t = tid + t0 * 256;
            int row = t >> 3;
            int c = t & 7;
            float4 v = make_float4(0.f, 0.f, 0.f, 0.f);
            if (m0 + row < M) v = load_a4(A, (size_t)(m0 + row) * K + k0 + c * 4);
            As[(c * 4 + 0) * 68 + row] = v.x;
            As[(c * 4 + 1) * 68 + row] = v.y;
            As[(c * 4 + 2) * 68 + row] = v.z;
            As[(c * 4 + 3) * 68 + row] = v.w;
        }
#pragma unroll
        for (int t0 = 0; t0 < 32 * TN4 / 256; t0++) {
            int t = tid + t0 * 256;
            int r = t / TN4;
            int c4 = t % TN4;
            *reinterpret_cast<float4*>(&Bs[r * TN + c4 * 4]) =
                *reinterpret_cast<const float4*>(&W[(size_t)(k0 + r) * TN + c4 * 4]);
        }
        __syncthreads();
#pragma unroll 8
        for (int k = 0; k < 32; k++) {
            float4 a0 = *reinterpret_cast<float4*>(&As[k * 68 + ty * 8]);
            float4 a1 = *reinterpret_cast<float4*>(&As[k * 68 + ty * 8 + 4]);
            float ar[8] = {a0.x, a0.y, a0.z, a0.w, a1.x, a1.y, a1.z, a1.w};
            float br[NJ];
#pragma unroll
            for (int j = 0; j < NJ; j++) br[j] = Bs[k * TN + tx + 32 * j];
#pragma unroll
            for (int i = 0; i < 8; i++)
#pragma unroll
                for (int j = 0; j < NJ; j++) acc[i][j] = fmaf(ar[i], br[j], acc[i][j]);
        }
        __syncthreads();
    }
#pragma unroll
    for (int i = 0; i < 8; i++) {
        int row = m0 + ty * 8 + i;
        if (row < M) {
            float sc = SCALE ? rowscale[row] : 1.f;
#pragma unroll
            for (int j = 0; j < NJ; j++) {
                float v = acc[i][j] + (BIAS ? bias[tx + 32 * j] : 0.f);
                if (RELU) v = fmaxf(v, 0.f);
                v *= sc;
                out[(size_t)row * TN + tx + 32 * j] = (OT)v;
            }
        }
    }
}

// ---------------- K1: projections (fp16 out) || rank (2 atomics/edge) ----------------

__global__ __launch_bounds__(256) void k1_proj_rank(
    const float* __restrict__ feat0, const float* __restrict__ feat1, const float* __restrict__ feat2,
    const float* __restrict__ W0, const float* __restrict__ b0,
    const float* __restrict__ W1, const float* __restrict__ b1,
    const float* __restrict__ W2, const float* __restrict__ b2,
    __half* __restrict__ h0h,
    const int* __restrict__ src, const int* __restrict__ dst,
    int* __restrict__ cnt, int* __restrict__ degO, int* __restrict__ rank) {
    __shared__ float As[32 * 68];
    __shared__ float Bs[32 * 128];
    int bid = blockIdx.x;
    if (bid < PB_TOTAL) {
        const float* A; const float* Wp; const float* bp; __half* op; int M, K, m0;
        if (bid < PB0) {
            A = feat0; Wp = W0; bp = b0; op = h0h; M = N0_; K = 512; m0 = bid * 64;
        } else if (bid < PB0 + PB1) {
            A = feat1; Wp = W1; bp = b1; op = h0h + (size_t)N0_ * H_; M = N1_; K = 256;
            m0 = (bid - PB0) * 64;
        } else {
            A = feat2; Wp = W2; bp = b2; op = h0h + (size_t)(N0_ + N1_) * H_; M = N2_; K = 128;
            m0 = (bid - PB0 - PB1) * 64;
        }
        gemm_block<128, true, false, false, float, __half>(A, Wp, bp, nullptr, op, M, K, m0, As, Bs);
    } else {
        int e = (bid - PB_TOTAL) * 256 + threadIdx.x;
        if (e < E_EDGES) {
            rank[e] = atomicAdd(&cnt[dst[e]], 1);
            atomicAdd(&degO[src[e]], 1);
        }
    }
}

// ---------------- hierarchical scan + norms; fill merged into scan3 ----------------

__global__ __launch_bounds__(256) void scan1_kernel(
    const int* __restrict__ cnt, int* __restrict__ pre, int* __restrict__ blocksum) {
    __shared__ int buf[256];
    int t = threadIdx.x;
    int i = blockIdx.x * 256 + t;
    int tot = (i < N_NODES) ? cnt[i] : 0;
    buf[t] = tot;
    __syncthreads();
#pragma unroll
    for (int off = 1; off < 256; off <<= 1) {
        int v = (t >= off) ? buf[t - off] : 0;
        __syncthreads();
        buf[t] += v;
        __syncthreads();
    }
    if (i < N_NODES) pre[i] = buf[t] - tot;
    if (t == 255) blocksum[blockIdx.x] = buf[255];
}

__global__ __launch_bounds__(256) void scan2_kernel(
    const int* __restrict__ blocksum, int* __restrict__ blockoff, int* __restrict__ rowptr) {
    __shared__ int buf[256];
    int t = threadIdx.x;
    int v = (t < SB) ? blocksum[t] : 0;
    buf[t] = v;
    __syncthreads();
#pragma unroll
    for (int off = 1; off < 256; off <<= 1) {
        int u = (t >= off) ? buf[t - off] : 0;
        __syncthreads();
        buf[t] += u;
        __syncthreads();
    }
    if (t < SB) blockoff[t] = buf[t] - v;
    if (t == 255) rowptr[N_NODES] = buf[255];
}

__global__ __launch_bounds__(256) void scan3_fill_kernel(
    const int* __restrict__ cnt, const int* __restrict__ degO, const int* __restrict__ pre,
    const int* __restrict__ blockoff, int* __restrict__ rowptr,
    float* __restrict__ ns, float* __restrict__ nd,
    const int* __restrict__ src, const int* __restrict__ dst,
    const int* __restrict__ rank, int* __restrict__ col) {
    int bid = blockIdx.x;
    if (bid < SB) {
        int i = bid * 256 + threadIdx.x;
        if (i < N_NODES) {
            rowptr[i] = blockoff[bid] + pre[i];
            ns[i] = rsqrtf(fmaxf((float)degO[i], 1.0f));
            nd[i] = rsqrtf(fmaxf((float)cnt[i], 1.0f));
        }
    } else {
        int e = (bid - SB) * 256 + threadIdx.x;
        if (e < E_EDGES) {
            int d = dst[e];
            int rp = blockoff[d >> 8] + pre[d];
            col[rp + rank[e]] = src[e];
        }
    }
}

// ---------------- fp16-gather aggregation (DEPTH=2 proven shape) ----------------

template <int CH, int NSLOAD, int EPI, int OUTH>
__global__ __launch_bounds__(256) void agg_h_kernel(
    const __half* __restrict__ h, const int* __restrict__ rowptr,
    const int* __restrict__ col, const float* __restrict__ ns,
    const float* __restrict__ nd, const float* __restrict__ bias,
    void* __restrict__ out) {
    constexpr int L = CH / 8;
    constexpr int EPW = 64 / L;
    int node = blockIdx.x * 4 + (threadIdx.x >> 6);
    if (node >= N_NODES) return;
    int lane = threadIdx.x & 63;
    int li = lane & (L - 1);
    int g = lane / L;
    const uint4* __restrict__ h8 = (const uint4*)h;
    int beg = rowptr[node], end = rowptr[node + 1];
    float a0[8] = {0.f, 0.f, 0.f, 0.f, 0.f, 0.f, 0.f, 0.f};
    float a1[8] = {0.f, 0.f, 0.f, 0.f, 0.f, 0.f, 0.f, 0.f};
    union U8 { uint4 u; __half2 h2[4]; };
    int e = beg + g;
    for (; e + EPW < end; e += 2 * EPW) {
        int s0 = col[e], s1 = col[e + EPW];
        U8 u0, u1;
        u0.u = h8[(size_t)s0 * L + li];
        u1.u = h8[(size_t)s1 * L + li];
        float w0 = NSLOAD ? ns[s0] : 1.f;
        float w1 = NSLOAD ? ns[s1] : 1.f;
#pragma unroll
        for (int p = 0; p < 4; p++) {
            float2 f0 = __half22float2(u0.h2[p]);
            float2 f1 = __half22float2(u1.h2[p]);
            if (NSLOAD) {
                a0[2 * p] = fmaf(w0, f0.x, a0[2 * p]);
                a0[2 * p + 1] = fmaf(w0, f0.y, a0[2 * p + 1]);
                a1[2 * p] = fmaf(w1, f1.x, a1[2 * p]);
                a1[2 * p + 1] = fmaf(w1, f1.y, a1[2 * p + 1]);
            } else {
                a0[2 * p] += f0.x;
                a0[2 * p + 1] += f0.y;
                a1[2 * p] += f1.x;
                a1[2 * p + 1] += f1.y;
            }
        }
    }
    if (e < end) {
        int s = col[e];
        U8 u0;
        u0.u = h8[(size_t)s * L + li];
        float w0 = NSLOAD ? ns[s] : 1.f;
#pragma unroll
        for (int p = 0; p < 4; p++) {
            float2 f0 = __half22float2(u0.h2[p]);
            if (NSLOAD) {
                a0[2 * p] = fmaf(w0, f0.x, a0[2 * p]);
                a0[2 * p + 1] = fmaf(w0, f0.y, a0[2 * p + 1]);
            } else {
                a0[2 * p] += f0.x;
                a0[2 * p + 1] += f0.y;
            }
        }
    }
#pragma unroll
    for (int j = 0; j < 8; j++) {
        float v = a0[j] + a1[j];
#pragma unroll
        for (int off = 32; off >= L; off >>= 1) v += __shfl_xor(v, off);
        a0[j] = v;
    }
    if (lane < L) {
        float w = nd[node];
#pragma unroll
        for (int j = 0; j < 8; j++) a0[j] *= w;
        if (EPI == 1) {
            float sc = ns[node];
#pragma unroll
            for (int j = 0; j < 8; j++)
                a0[j] = fmaxf(a0[j] + bias[li * 8 + j], 0.f) * sc;
        } else if (EPI == 2) {
#pragma unroll
            for (int j = 0; j < 8; j++) a0[j] += bias[li * 8 + j];
        }
        if (OUTH) {
            union { uint4 u; __half hh[8]; } cv;
#pragma unroll
            for (int j = 0; j < 8; j++) cv.hh[j] = __float2half(a0[j]);
            ((uint4*)out)[(size_t)node * L + li] = cv.u;
        } else {
            float4* o4 = (float4*)out;
            o4[(size_t)node * (CH / 4) + li * 2] = make_float4(a0[0], a0[1], a0[2], a0[3]);
            o4[(size_t)node * (CH / 4) + li * 2 + 1] = make_float4(a0[4], a0[5], a0[6], a0[7]);
        }
    }
}

// ---------------- fused middle: agg1-gather -> GEMM1(relu) -> GEMM2(*ns) ----------
// One block per 64 nodes. Phase 1: gather each of the block's rows (agg of h1h,
// *nd) into LDS Ar[row][k] fp16 (stride 136 halves: 16-lane writes 2-way = free).
// Phase 2: C1 = relu(Ar @ W_l1 + b_l1) -> overwrite Ar (fp16). Phase 3:
// h2h = ns_row * (C1 @ W_l2). A-reads are 2-address wave broadcasts (free);
// B staging/reads use the proven conflict-free patterns. Legal per-block fusion:
// gather row i depends only on complete h1h + CSR; diag(ns) commutes with @W.

__global__ __launch_bounds__(256) void fused_mid_kernel(
    const __half* __restrict__ h, const int* __restrict__ rowptr,
    const int* __restrict__ col, const float* __restrict__ ns,
    const float* __restrict__ nd,
    const float* __restrict__ Wl1, const float* __restrict__ bl1,
    const float* __restrict__ Wl2,
    __half* __restrict__ h2h) {
    __shared__ __half Ar[64 * 136];
    __shared__ float Bs[32 * 128];
    int tid = threadIdx.x;
    int m0 = blockIdx.x * 64;
    int lane = tid & 63;
    int li = lane & 15;
    int g = lane >> 4;
    const uint4* __restrict__ h8 = (const uint4*)h;

    // ---- phase 1: gather 64 rows ----
    for (int pass = 0; pass < 16; pass++) {
        int row = pass * 4 + (tid >> 6);
        int node = m0 + row;
        float a0[8] = {0.f, 0.f, 0.f, 0.f, 0.f, 0.f, 0.f, 0.f};
        float a1[8] = {0.f, 0.f, 0.f, 0.f, 0.f, 0.f, 0.f, 0.f};
        union U8 { uint4 u; __half2 h2[4]; };
        if (node < N_NODES) {
            int beg = rowptr[node], end = rowptr[node + 1];
            int e = beg + g;
            for (; e + 4 < end; e += 8) {
                int s0 = col[e], s1 = col[e + 4];
                U8 u0, u1;
                u0.u = h8[(size_t)s0 * 16 + li];
                u1.u = h8[(size_t)s1 * 16 + li];
#pragma unroll
                for (int p = 0; p < 4; p++) {
                    float2 f0 = __half22float2(u0.h2[p]);
                    float2 f1 = __half22float2(u1.h2[p]);
                    a0[2 * p] += f0.x;
                    a0[2 * p + 1] += f0.y;
                    a1[2 * p] += f1.x;
                    a1[2 * p + 1] += f1.y;
                }
            }
            if (e < end) {
                int s = col[e];
                U8 u0;
                u0.u = h8[(size_t)s * 16 + li];
#pragma unroll
                for (int p = 0; p < 4; p++) {
                    float2 f0 = __half22float2(u0.h2[p]);
                    a0[2 * p] += f0.x;
                    a0[2 * p + 1] += f0.y;
                }
            }
        }
#pragma unroll
        for (int j = 0; j < 8; j++) {
            float v = a0[j] + a1[j];
            v += __shfl_xor(v, 32);
            v += __shfl_xor(v, 16);
            a0[j] = v;
        }
        if (lane < 16) {
            float w = (node < N_NODES) ? nd[node] : 0.f;
#pragma unroll
            for (int j = 0; j < 8; j++)
                Ar[row * 136 + li * 8 + j] = __float2half(a0[j] * w);
        }
    }
    __syncthreads();

    // ---- phase 2: C1 = relu(Ar @ W_l1 + b_l1) ----
    int tx = tid & 31;
    int ty = tid >> 5;
    float acc[8][4];
#pragma unroll
    for (int i = 0; i < 8; i++)
#pragma unroll
        for (int j = 0; j < 4; j++) acc[i][j] = 0.f;

    for (int k0 = 0; k0 < 128; k0 += 32) {
#pragma unroll
        for (int t0 = 0; t0 < 4; t0++) {
            int idx = tid + t0 * 256;
            int r = idx >> 5;
            int c4 = idx & 31;
            *reinterpret_cast<float4*>(&Bs[r * 128 + c4 * 4]) =
                *reinterpret_cast<const float4*>(&Wl1[(size_t)(k0 + r) * 128 + c4 * 4]);
        }
        __syncthreads();
#pragma unroll 8
        for (int k = 0; k < 32; k++) {
            float ar[8];
#pragma unroll
            for (int i = 0; i < 8; i++) ar[i] = __half2float(Ar[(ty * 8 + i) * 136 + k0 + k]);
            float br[4];
#pragma unroll
            for (int j = 0; j < 4; j++) br[j] = Bs[k * 128 + tx + 32 * j];
#pragma unroll
            for (int i = 0; i < 8; i++)
#pragma unroll
                for (int j = 0; j < 4; j++) acc[i][j] = fmaf(ar[i], br[j], acc[i][j]);
        }
        __syncthreads();
    }
#pragma unroll
    for (int i = 0; i < 8; i++) {
        int row = ty * 8 + i;
#pragma unroll
        for (int j = 0; j < 4; j++)
            Ar[row * 136 + tx + 32 * j] =
                __float2half(fmaxf(acc[i][j] + bl1[tx + 32 * j], 0.f));
    }
    __syncthreads();

    // ---- phase 3: h2h = ns_row * (C1 @ W_l2) ----
    float acc2[8][2];
#pragma unroll
    for (int i = 0; i < 8; i++) {
        acc2[i][0] = 0.f;
        acc2[i][1] = 0.f;
    }
    for (int k0 = 0; k0 < 128; k0 += 32) {
#pragma unroll
        for (int t0 = 0; t0 < 2; t0++) {
            int idx = tid + t0 * 256;
            int r = idx >> 4;
            int c4 = idx & 15;
            *reinterpret_cast<float4*>(&Bs[r * 64 + c4 * 4]) =
                *reinterpret_cast<const float4*>(&Wl2[(size_t)(k0 + r) * 64 + c4 * 4]);
        }
        __syncthreads();
#pragma unroll 8
        for (int k = 0; k < 32; k++) {
            float ar[8];
#pragma unroll
            for (int i = 0; i < 8; i++) ar[i] = __half2float(Ar[(ty * 8 + i) * 136 + k0 + k]);
            float b0v = Bs[k * 64 + tx];
            float b1v = Bs[k * 64 + tx + 32];
#pragma unroll
            for (int i = 0; i < 8; i++) {
                acc2[i][0] = fmaf(ar[i], b0v, acc2[i][0]);
                acc2[i][1] = fmaf(ar[i], b1v, acc2[i][1]);
            }
        }
        __syncthreads();
    }
#pragma unroll
    for (int i = 0; i < 8; i++) {
        int row = m0 + ty * 8 + i;
        if (row < N_NODES) {
            float sc = ns[row];
            h2h[(size_t)row * 64 + tx] = __float2half(acc2[i][0] * sc);
            h2h[(size_t)row * 64 + tx + 32] = __float2half(acc2[i][1] * sc);
        }
    }
}

// ---------------- launch ----------------

extern "C" void kernel_launch(void* const* d_in, const int* in_sizes, int n_in,
                              void* d_out, int out_size, void* d_ws, size_t ws_size,
                              hipStream_t stream) {
    const float* feat0 = (const float*)d_in[0];
    const float* feat1 = (const float*)d_in[1];
    const float* feat2 = (const float*)d_in[2];
    const float* W0 = (const float*)d_in[3];
    const float* b0 = (const float*)d_in[4];
    const float* W1 = (const float*)d_in[5];
    const float* b1 = (const float*)d_in[6];
    const float* W2 = (const float*)d_in[7];
    const float* b2 = (const float*)d_in[8];
    const float* bias_l0 = (const float*)d_in[9];
    const float* W_l1 = (const float*)d_in[10];
    const float* b_l1 = (const float*)d_in[11];
    const float* W_l2 = (const float*)d_in[12];
    const float* b_l2 = (const float*)d_in[13];
    const int* src = (const int*)d_in[14];
    const int* dst = (const int*)d_in[15];
    float* out = (float*)d_out;

    char* ws = (char*)d_ws;
    size_t off = 0;
    auto alloc = [&](size_t bytes) {
        size_t cur = off;
        off += (bytes + 255) & ~(size_t)255;
        return cur;
    };
    size_t h0h_off = alloc((size_t)N_NODES * H_ * 2);   // proj out (fp16)
    size_t h1h_off = alloc((size_t)N_NODES * H_ * 2);   // agg0 out (fp16)
    size_t h2h_off = alloc((size_t)N_NODES * C_ * 2);   // fused_mid out (fp16)
    size_t cnt_off = alloc((size_t)N_NODES * 4);        // zeroed each call
    size_t degO_off = alloc((size_t)N_NODES * 4);       // zeroed each call
    size_t ns_off = alloc((size_t)N_NODES * 4);
    size_t nd_off = alloc((size_t)N_NODES * 4);
    size_t rowptr_off = alloc((size_t)(N_NODES + 1) * 4);
    size_t rank_off = alloc((size_t)E_EDGES * 4);
    size_t col_off = alloc((size_t)E_EDGES * 4);
    size_t pre_off = alloc((size_t)N_NODES * 4);
    size_t bsum_off = alloc((size_t)SB * 4);
    size_t boff_off = alloc((size_t)SB * 4);

    __half* h0h = (__half*)(ws + h0h_off);
    __half* h1h = (__half*)(ws + h1h_off);
    __half* h2h = (__half*)(ws + h2h_off);
    int* cnt = (int*)(ws + cnt_off);
    int* degO = (int*)(ws + degO_off);
    float* ns = (float*)(ws + ns_off);
    float* nd = (float*)(ws + nd_off);
    int* rowptr = (int*)(ws + rowptr_off);
    int* rank = (int*)(ws + rank_off);
    int* col = (int*)(ws + col_off);
    int* pre = (int*)(ws + pre_off);
    int* bsum = (int*)(ws + bsum_off);
    int* boff = (int*)(ws + boff_off);

    hipMemsetAsync(ws + cnt_off, 0, ns_off - cnt_off, stream);  // cnt + degO

    // K1: projections (fp16 h0) || rank
    k1_proj_rank<<<PB_TOTAL + EB, 256, 0, stream>>>(
        feat0, feat1, feat2, W0, b0, W1, b1, W2, b2, h0h, src, dst, cnt, degO, rank);
    // hierarchical scan; norms + col-fill merged into the third stage
    scan1_kernel<<<SB, 256, 0, stream>>>(cnt, pre, bsum);
    scan2_kernel<<<1, 256, 0, stream>>>(bsum, boff, rowptr);
    scan3_fill_kernel<<<SB + EB, 256, 0, stream>>>(
        cnt, degO, pre, boff, rowptr, ns, nd, src, dst, rank, col);

    const int AGB = (N_NODES + 3) / 4;
    // layer 0: fp16 gather (ns-weighted), +bias, relu, *ns -> fp16 h1
    agg_h_kernel<128, 1, 1, 1><<<AGB, 256, 0, stream>>>(h0h, rowptr, col, ns, nd, bias_l0, h1h);
    // fused middle: agg1 -> GEMM(W_l1)+relu -> GEMM(W_l2)*ns -> fp16 h2h
    fused_mid_kernel<<<FB, 256, 0, stream>>>(h1h, rowptr, col, ns, nd, W_l1, b_l1, W_l2, h2h);
    // final: 64-ch fp16 agg + bias -> fp32 out
    agg_h_kernel<64, 0, 2, 0><<<AGB, 256, 0, stream>>>(h2h, rowptr, col, ns, nd, b_l2, out);
}

// Round 18
// 255.572 us; speedup vs baseline: 1.1615x; 1.1615x over previous
//
#include <hip/hip_runtime.h>
#include <hip/hip_fp16.h>

#define N_NODES 50000
#define N0_ 20000
#define N1_ 15000
#define N2_ 15000
#define E_EDGES 800000
#define H_ 128
#define C_ 64

#define PB0 ((N0_ + 63) / 64)              // 313
#define PB1 ((N1_ + 63) / 64)              // 235
#define PB2 ((N2_ + 63) / 64)              // 235
#define PB_TOTAL (PB0 + PB1 + PB2)         // 783
#define EB ((E_EDGES + 255) / 256)         // 3125
#define SB ((N_NODES + 255) / 256)         // 196

// ---- A-tile loaders: fp32 direct, fp16 -> fp32 convert (FMA stays fp32) ----
__device__ __forceinline__ float4 load_a4(const float* A, size_t idx) {
    return *reinterpret_cast<const float4*>(&A[idx]);
}
__device__ __forceinline__ float4 load_a4(const __half* A, size_t idx) {
    __half2 p0 = *reinterpret_cast<const __half2*>(&A[idx]);
    __half2 p1 = *reinterpret_cast<const __half2*>(&A[idx + 2]);
    float2 f0 = __half22float2(p0), f1 = __half22float2(p1);
    return make_float4(f0.x, f0.y, f1.x, f1.y);
}

// ---------------- GEMM block (64-row tile, R3/R8/R10/R16-proven) ----------------
// A transposed in LDS (stride 68); B-reads scalar stride-1 across tx (conflict-free).
// Ledger: DEPTH-4, MFMA x2, dot2 x2, mid-fusion all regressed; this is the proven best.

template <int TN, bool BIAS, bool RELU, bool SCALE, typename IT, typename OT>
__device__ __forceinline__ void gemm_block(
    const IT* __restrict__ A, const float* __restrict__ W,
    const float* __restrict__ bias, const float* __restrict__ rowscale,
    OT* __restrict__ out, int M, int K, int m0, float* As, float* Bs) {
    constexpr int NJ = TN / 32;
    constexpr int TN4 = TN / 4;
    int tid = threadIdx.x;
    int tx = tid & 31;
    int ty = tid >> 5;

    float acc[8][NJ];
#pragma unroll
    for (int i = 0; i < 8; i++)
#pragma unroll
        for (int j = 0; j < NJ; j++) acc[i][j] = 0.f;

    for (int k0 = 0; k0 < K; k0 += 32) {
#pragma unroll
        for (int t0 = 0; t0 < 2; t0++) {
            int t = tid + t0 * 256;
            int row = t >> 3;
            int c = t & 7;
            float4 v = make_float4(0.f, 0.f, 0.f, 0.f);
            if (m0 + row < M) v = load_a4(A, (size_t)(m0 + row) * K + k0 + c * 4);
            As[(c * 4 + 0) * 68 + row] = v.x;
            As[(c * 4 + 1) * 68 + row] = v.y;
            As[(c * 4 + 2) * 68 + row] = v.z;
            As[(c * 4 + 3) * 68 + row] = v.w;
        }
#pragma unroll
        for (int t0 = 0; t0 < 32 * TN4 / 256; t0++) {
            int t = tid + t0 * 256;
            int r = t / TN4;
            int c4 = t % TN4;
            *reinterpret_cast<float4*>(&Bs[r * TN + c4 * 4]) =
                *reinterpret_cast<const float4*>(&W[(size_t)(k0 + r) * TN + c4 * 4]);
        }
        __syncthreads();
#pragma unroll 8
        for (int k = 0; k < 32; k++) {
            float4 a0 = *reinterpret_cast<float4*>(&As[k * 68 + ty * 8]);
            float4 a1 = *reinterpret_cast<float4*>(&As[k * 68 + ty * 8 + 4]);
            float ar[8] = {a0.x, a0.y, a0.z, a0.w, a1.x, a1.y, a1.z, a1.w};
            float br[NJ];
#pragma unroll
            for (int j = 0; j < NJ; j++) br[j] = Bs[k * TN + tx + 32 * j];
#pragma unroll
            for (int i = 0; i < 8; i++)
#pragma unroll
                for (int j = 0; j < NJ; j++) acc[i][j] = fmaf(ar[i], br[j], acc[i][j]);
        }
        __syncthreads();
    }
#pragma unroll
    for (int i = 0; i < 8; i++) {
        int row = m0 + ty * 8 + i;
        if (row < M) {
            float sc = SCALE ? rowscale[row] : 1.f;
#pragma unroll
            for (int j = 0; j < NJ; j++) {
                float v = acc[i][j] + (BIAS ? bias[tx + 32 * j] : 0.f);
                if (RELU) v = fmaxf(v, 0.f);
                v *= sc;
                out[(size_t)row * TN + tx + 32 * j] = (OT)v;
            }
        }
    }
}

// ---------------- K1: projections (fp16 out) || rank (2 atomics/edge) ----------------

__global__ __launch_bounds__(256) void k1_proj_rank(
    const float* __restrict__ feat0, const float* __restrict__ feat1, const float* __restrict__ feat2,
    const float* __restrict__ W0, const float* __restrict__ b0,
    const float* __restrict__ W1, const float* __restrict__ b1,
    const float* __restrict__ W2, const float* __restrict__ b2,
    __half* __restrict__ h0h,
    const int* __restrict__ src, const int* __restrict__ dst,
    int* __restrict__ cnt, int* __restrict__ degO, int* __restrict__ rank) {
    __shared__ float As[32 * 68];
    __shared__ float Bs[32 * 128];
    int bid = blockIdx.x;
    if (bid < PB_TOTAL) {
        const float* A; const float* Wp; const float* bp; __half* op; int M, K, m0;
        if (bid < PB0) {
            A = feat0; Wp = W0; bp = b0; op = h0h; M = N0_; K = 512; m0 = bid * 64;
        } else if (bid < PB0 + PB1) {
            A = feat1; Wp = W1; bp = b1; op = h0h + (size_t)N0_ * H_; M = N1_; K = 256;
            m0 = (bid - PB0) * 64;
        } else {
            A = feat2; Wp = W2; bp = b2; op = h0h + (size_t)(N0_ + N1_) * H_; M = N2_; K = 128;
            m0 = (bid - PB0 - PB1) * 64;
        }
        gemm_block<128, true, false, false, float, __half>(A, Wp, bp, nullptr, op, M, K, m0, As, Bs);
    } else {
        int e = (bid - PB_TOTAL) * 256 + threadIdx.x;
        if (e < E_EDGES) {
            rank[e] = atomicAdd(&cnt[dst[e]], 1);
            atomicAdd(&degO[src[e]], 1);
        }
    }
}

// ---------------- hierarchical scan + norms; fill merged into scan3 ----------------

__global__ __launch_bounds__(256) void scan1_kernel(
    const int* __restrict__ cnt, int* __restrict__ pre, int* __restrict__ blocksum) {
    __shared__ int buf[256];
    int t = threadIdx.x;
    int i = blockIdx.x * 256 + t;
    int tot = (i < N_NODES) ? cnt[i] : 0;
    buf[t] = tot;
    __syncthreads();
#pragma unroll
    for (int off = 1; off < 256; off <<= 1) {
        int v = (t >= off) ? buf[t - off] : 0;
        __syncthreads();
        buf[t] += v;
        __syncthreads();
    }
    if (i < N_NODES) pre[i] = buf[t] - tot;
    if (t == 255) blocksum[blockIdx.x] = buf[255];
}

__global__ __launch_bounds__(256) void scan2_kernel(
    const int* __restrict__ blocksum, int* __restrict__ blockoff, int* __restrict__ rowptr) {
    __shared__ int buf[256];
    int t = threadIdx.x;
    int v = (t < SB) ? blocksum[t] : 0;
    buf[t] = v;
    __syncthreads();
#pragma unroll
    for (int off = 1; off < 256; off <<= 1) {
        int u = (t >= off) ? buf[t - off] : 0;
        __syncthreads();
        buf[t] += u;
        __syncthreads();
    }
    if (t < SB) blockoff[t] = buf[t] - v;
    if (t == 255) rowptr[N_NODES] = buf[255];
}

// blocks [0,SB): rowptr + norms. blocks [SB,SB+EB): col fill, computing the
// destination rowptr inline from blockoff+pre (no dependency on scan3's output).
__global__ __launch_bounds__(256) void scan3_fill_kernel(
    const int* __restrict__ cnt, const int* __restrict__ degO, const int* __restrict__ pre,
    const int* __restrict__ blockoff, int* __restrict__ rowptr,
    float* __restrict__ ns, float* __restrict__ nd,
    const int* __restrict__ src, const int* __restrict__ dst,
    const int* __restrict__ rank, int* __restrict__ col) {
    int bid = blockIdx.x;
    if (bid < SB) {
        int i = bid * 256 + threadIdx.x;
        if (i < N_NODES) {
            rowptr[i] = blockoff[bid] + pre[i];
            ns[i] = rsqrtf(fmaxf((float)degO[i], 1.0f));
            nd[i] = rsqrtf(fmaxf((float)cnt[i], 1.0f));
        }
    } else {
        int e = (bid - SB) * 256 + threadIdx.x;
        if (e < E_EDGES) {
            int d = dst[e];
            int rp = blockoff[d >> 8] + pre[d];
            col[rp + rank[e]] = src[e];
        }
    }
}

// ---------------- fp16-gather aggregation (DEPTH=2 proven shape) ----------------
// CH channels; L=CH/8 lanes/edge (16B/lane), EPW=64/L edges/wave/iter.
// fp32 accumulate. EPI 0: *nd. EPI 1: *nd,+bias,relu,*ns. EPI 2: *nd,+bias (final).
// OUTH: fp16/fp32 out.

template <int CH, int NSLOAD, int EPI, int OUTH>
__global__ __launch_bounds__(256) void agg_h_kernel(
    const __half* __restrict__ h, const int* __restrict__ rowptr,
    const int* __restrict__ col, const float* __restrict__ ns,
    const float* __restrict__ nd, const float* __restrict__ bias,
    void* __restrict__ out) {
    constexpr int L = CH / 8;
    constexpr int EPW = 64 / L;
    int node = blockIdx.x * 4 + (threadIdx.x >> 6);
    if (node >= N_NODES) return;
    int lane = threadIdx.x & 63;
    int li = lane & (L - 1);
    int g = lane / L;
    const uint4* __restrict__ h8 = (const uint4*)h;
    int beg = rowptr[node], end = rowptr[node + 1];
    float a0[8] = {0.f, 0.f, 0.f, 0.f, 0.f, 0.f, 0.f, 0.f};
    float a1[8] = {0.f, 0.f, 0.f, 0.f, 0.f, 0.f, 0.f, 0.f};
    union U8 { uint4 u; __half2 h2[4]; };
    int e = beg + g;
    for (; e + EPW < end; e += 2 * EPW) {
        int s0 = col[e], s1 = col[e + EPW];
        U8 u0, u1;
        u0.u = h8[(size_t)s0 * L + li];
        u1.u = h8[(size_t)s1 * L + li];
        float w0 = NSLOAD ? ns[s0] : 1.f;
        float w1 = NSLOAD ? ns[s1] : 1.f;
#pragma unroll
        for (int p = 0; p < 4; p++) {
            float2 f0 = __half22float2(u0.h2[p]);
            float2 f1 = __half22float2(u1.h2[p]);
            if (NSLOAD) {
                a0[2 * p] = fmaf(w0, f0.x, a0[2 * p]);
                a0[2 * p + 1] = fmaf(w0, f0.y, a0[2 * p + 1]);
                a1[2 * p] = fmaf(w1, f1.x, a1[2 * p]);
                a1[2 * p + 1] = fmaf(w1, f1.y, a1[2 * p + 1]);
            } else {
                a0[2 * p] += f0.x;
                a0[2 * p + 1] += f0.y;
                a1[2 * p] += f1.x;
                a1[2 * p + 1] += f1.y;
            }
        }
    }
    if (e < end) {
        int s = col[e];
        U8 u0;
        u0.u = h8[(size_t)s * L + li];
        float w0 = NSLOAD ? ns[s] : 1.f;
#pragma unroll
        for (int p = 0; p < 4; p++) {
            float2 f0 = __half22float2(u0.h2[p]);
            if (NSLOAD) {
                a0[2 * p] = fmaf(w0, f0.x, a0[2 * p]);
                a0[2 * p + 1] = fmaf(w0, f0.y, a0[2 * p + 1]);
            } else {
                a0[2 * p] += f0.x;
                a0[2 * p + 1] += f0.y;
            }
        }
    }
#pragma unroll
    for (int j = 0; j < 8; j++) {
        float v = a0[j] + a1[j];
#pragma unroll
        for (int off = 32; off >= L; off >>= 1) v += __shfl_xor(v, off);
        a0[j] = v;
    }
    if (lane < L) {
        float w = nd[node];
#pragma unroll
        for (int j = 0; j < 8; j++) a0[j] *= w;
        if (EPI == 1) {
            float sc = ns[node];
#pragma unroll
            for (int j = 0; j < 8; j++)
                a0[j] = fmaxf(a0[j] + bias[li * 8 + j], 0.f) * sc;
        } else if (EPI == 2) {
#pragma unroll
            for (int j = 0; j < 8; j++) a0[j] += bias[li * 8 + j];
        }
        if (OUTH) {
            union { uint4 u; __half hh[8]; } cv;
#pragma unroll
            for (int j = 0; j < 8; j++) cv.hh[j] = __float2half(a0[j]);
            ((uint4*)out)[(size_t)node * L + li] = cv.u;
        } else {
            float4* o4 = (float4*)out;
            o4[(size_t)node * (CH / 4) + li * 2] = make_float4(a0[0], a0[1], a0[2], a0[3]);
            o4[(size_t)node * (CH / 4) + li * 2 + 1] = make_float4(a0[4], a0[5], a0[6], a0[7]);
        }
    }
}

// ---------------- standalone GEMM (64-row tile) ----------------

template <int TN, bool BIAS, bool RELU, bool SCALE, typename IT, typename OT>
__global__ __launch_bounds__(256) void gemm_kernel(
    const IT* __restrict__ A, const float* __restrict__ W,
    const float* __restrict__ bias, const float* __restrict__ rowscale,
    OT* __restrict__ out, int M, int K) {
    __shared__ float As[32 * 68];
    __shared__ float Bs[32 * TN];
    gemm_block<TN, BIAS, RELU, SCALE, IT, OT>(A, W, bias, rowscale, out, M, K, blockIdx.x * 64, As, Bs);
}

// ---------------- launch ----------------

extern "C" void kernel_launch(void* const* d_in, const int* in_sizes, int n_in,
                              void* d_out, int out_size, void* d_ws, size_t ws_size,
                              hipStream_t stream) {
    const float* feat0 = (const float*)d_in[0];
    const float* feat1 = (const float*)d_in[1];
    const float* feat2 = (const float*)d_in[2];
    const float* W0 = (const float*)d_in[3];
    const float* b0 = (const float*)d_in[4];
    const float* W1 = (const float*)d_in[5];
    const float* b1 = (const float*)d_in[6];
    const float* W2 = (const float*)d_in[7];
    const float* b2 = (const float*)d_in[8];
    const float* bias_l0 = (const float*)d_in[9];
    const float* W_l1 = (const float*)d_in[10];
    const float* b_l1 = (const float*)d_in[11];
    const float* W_l2 = (const float*)d_in[12];
    const float* b_l2 = (const float*)d_in[13];
    const int* src = (const int*)d_in[14];
    const int* dst = (const int*)d_in[15];
    float* out = (float*)d_out;

    char* ws = (char*)d_ws;
    size_t off = 0;
    auto alloc = [&](size_t bytes) {
        size_t cur = off;
        off += (bytes + 255) & ~(size_t)255;
        return cur;
    };
    size_t h0h_off = alloc((size_t)N_NODES * H_ * 2);   // proj out (fp16)
    size_t h1h_off = alloc((size_t)N_NODES * H_ * 2);   // agg0 out (fp16)
    size_t hAh_off = alloc((size_t)N_NODES * H_ * 2);   // agg1 out (fp16)
    size_t hBh_off = alloc((size_t)N_NODES * H_ * 2);   // gemm1 out (fp16)
    size_t h2h_off = alloc((size_t)N_NODES * C_ * 2);   // gemm2 out (fp16)
    size_t cnt_off = alloc((size_t)N_NODES * 4);        // zeroed each call
    size_t degO_off = alloc((size_t)N_NODES * 4);       // zeroed each call
    size_t ns_off = alloc((size_t)N_NODES * 4);
    size_t nd_off = alloc((size_t)N_NODES * 4);
    size_t rowptr_off = alloc((size_t)(N_NODES + 1) * 4);
    size_t rank_off = alloc((size_t)E_EDGES * 4);
    size_t col_off = alloc((size_t)E_EDGES * 4);
    size_t pre_off = alloc((size_t)N_NODES * 4);
    size_t bsum_off = alloc((size_t)SB * 4);
    size_t boff_off = alloc((size_t)SB * 4);

    __half* h0h = (__half*)(ws + h0h_off);
    __half* h1h = (__half*)(ws + h1h_off);
    __half* hAh = (__half*)(ws + hAh_off);
    __half* hBh = (__half*)(ws + hBh_off);
    __half* h2h = (__half*)(ws + h2h_off);
    int* cnt = (int*)(ws + cnt_off);
    int* degO = (int*)(ws + degO_off);
    float* ns = (float*)(ws + ns_off);
    float* nd = (float*)(ws + nd_off);
    int* rowptr = (int*)(ws + rowptr_off);
    int* rank = (int*)(ws + rank_off);
    int* col = (int*)(ws + col_off);
    int* pre = (int*)(ws + pre_off);
    int* bsum = (int*)(ws + bsum_off);
    int* boff = (int*)(ws + boff_off);

    hipMemsetAsync(ws + cnt_off, 0, ns_off - cnt_off, stream);  // cnt + degO

    // K1: projections (fp16 h0) || rank
    k1_proj_rank<<<PB_TOTAL + EB, 256, 0, stream>>>(
        feat0, feat1, feat2, W0, b0, W1, b1, W2, b2, h0h, src, dst, cnt, degO, rank);
    // hierarchical scan; norms + col-fill merged into the third stage
    scan1_kernel<<<SB, 256, 0, stream>>>(cnt, pre, bsum);
    scan2_kernel<<<1, 256, 0, stream>>>(bsum, boff, rowptr);
    scan3_fill_kernel<<<SB + EB, 256, 0, stream>>>(
        cnt, degO, pre, boff, rowptr, ns, nd, src, dst, rank, col);

    const int AGB = (N_NODES + 3) / 4;
    // layer 0: fp16 gather (ns-weighted), +bias, relu, *ns -> fp16 h1
    agg_h_kernel<128, 1, 1, 1><<<AGB, 256, 0, stream>>>(h0h, rowptr, col, ns, nd, bias_l0, h1h);
    // layer 1: fp16 gather (pre-scaled) -> fp16 hAh; GEMM (fp16 in/out) + bias + relu, *ns
    agg_h_kernel<128, 0, 0, 1><<<AGB, 256, 0, stream>>>(h1h, rowptr, col, ns, nd, nullptr, hAh);
    gemm_kernel<128, true, true, true, __half, __half><<<(N_NODES + 63) / 64, 256, 0, stream>>>(
        hAh, W_l1, b_l1, ns, hBh, N_NODES, 128);
    // layer 2 reordered: GEMM first (fp16 in/out, no bias), then 64-ch fp16 agg + bias
    gemm_kernel<64, false, false, false, __half, __half><<<(N_NODES + 63) / 64, 256, 0, stream>>>(
        hBh, W_l2, nullptr, nullptr, h2h, N_NODES, 128);
    agg_h_kernel<64, 0, 2, 0><<<AGB, 256, 0, stream>>>(h2h, rowptr, col, ns, nd, b_l2, out);
}